// Round 1
// baseline (315.077 us; speedup 1.0000x reference)
//
#include <hip/hip_runtime.h>

// SimpleAttentionLayer: out[b,n,s] = softmax_s( sum_k tanh(enc[s,b,n,:]·W[k,:] + b[k]) * dec[b,n,k] )
// S=64, B=32, N=325, H=64. fp32 throughout.
//
// Design: one wave per (b,n); lane = s (64 lanes = 64 seq positions).
// - enc row per lane in 64 VGPRs (float4 x16 loads, all bytes of each line used)
// - W/bias/dec are wave-uniform -> s_load + v_fmac with SGPR operand (1 instr/MAC)
// - 4 accumulator chains to cover FMA latency (4cyc lat, 2cyc issue)
// - tanh(x) = 1 - 2/(exp(2x)+1), overflow-safe; softmax via 64-lane shfl butterfly

constexpr int S = 64, B = 32, N = 325, H = 64;
constexpr int BN = B * N;  // 10400

__global__ __launch_bounds__(256, 4) void attn_fused(
    const float* __restrict__ enc,   // (S,B,N,H)
    const float* __restrict__ dec,   // (B,N,H)
    const float* __restrict__ W,     // (H,H)  row k = output feature k
    const float* __restrict__ bias,  // (H)
    float* __restrict__ out)         // (B,N,S)
{
    const int lane = threadIdx.x & 63;                                   // s
    const int wave = __builtin_amdgcn_readfirstlane(threadIdx.x >> 6);   // force SGPR
    const int bn   = blockIdx.x * 4 + wave;                              // uniform per wave

    // Load this lane's encoder row: enc[(s*BN + bn)*H .. +63]
    const float4* erow = (const float4*)(enc + (lane * BN + bn) * H);
    float4 er[16];
#pragma unroll
    for (int i = 0; i < 16; ++i) er[i] = erow[i];

    const float* drow = dec + bn * H;   // uniform address per wave

    float e_s = 0.0f;
#pragma unroll 2
    for (int k = 0; k < H; ++k) {
        const float4* wrow = (const float4*)(W + k * H);  // uniform -> s_load
        float a0 = bias[k], a1 = 0.0f, a2 = 0.0f, a3 = 0.0f;
#pragma unroll
        for (int i = 0; i < 16; ++i) {
            float4 w = wrow[i];
            a0 = fmaf(er[i].x, w.x, a0);
            a1 = fmaf(er[i].y, w.y, a1);
            a2 = fmaf(er[i].z, w.z, a2);
            a3 = fmaf(er[i].w, w.w, a3);
        }
        float a = (a0 + a1) + (a2 + a3);
        // tanh(a) = 1 - 2/(exp(2a)+1); safe for +-inf of exp
        float t  = __expf(2.0f * a);
        float th = 1.0f - 2.0f * __builtin_amdgcn_rcpf(t + 1.0f);
        e_s = fmaf(th, drow[k], e_s);
    }

    // softmax over s = the 64 lanes of this wave
    float m = e_s;
#pragma unroll
    for (int off = 32; off > 0; off >>= 1)
        m = fmaxf(m, __shfl_xor(m, off, 64));
    float p = __expf(e_s - m);
    float sum = p;
#pragma unroll
    for (int off = 32; off > 0; off >>= 1)
        sum += __shfl_xor(sum, off, 64);

    out[bn * S + lane] = p * __builtin_amdgcn_rcpf(sum);
}

extern "C" void kernel_launch(void* const* d_in, const int* in_sizes, int n_in,
                              void* d_out, int out_size, void* d_ws, size_t ws_size,
                              hipStream_t stream) {
    const float* enc  = (const float*)d_in[0];
    const float* dec  = (const float*)d_in[1];
    const float* W    = (const float*)d_in[2];
    const float* bias = (const float*)d_in[3];
    float* out        = (float*)d_out;

    dim3 grid(BN / 4);   // 2600 blocks, 4 waves each = 10400 waves = one per (b,n)
    attn_fused<<<grid, 256, 0, stream>>>(enc, dec, W, bias, out);
}